// Round 1
// baseline (123.263 us; speedup 1.0000x reference)
//
#include <hip/hip_runtime.h>

#define P_SWAP 0.5f

// Resolve the sequential copy-chain into a per-frame source index.
// c[i]: >=0 means out[i] = video[c[i]] directly; -1 (PREV) means
// out[i] = out[i-1], which resolves to the nearest non-PREV c[j], j<i.
__global__ void resolve_src(const float* __restrict__ coin,
                            const int* __restrict__ nbr,
                            int* __restrict__ src, int N) {
    __shared__ int c[1024];
    int i = threadIdx.x;
    if (i < N) {
        bool d = coin[i] < P_SWAP;
        int v;
        if (!d)               v = i;          // keep own frame
        else if (i == 0)      v = (N > 1) ? 1 : 0;  // always orig next
        else if (i == N - 1)  v = -1;         // always out[N-2]
        else                  v = (nbr[i] == 0) ? -1 : (i + 1);
        c[i] = v;
    }
    __syncthreads();
    if (i < N) {
        int j = i;
        while (c[j] < 0) j--;                 // c[0] is never <0
        src[i] = c[j];
    }
}

// out[frame] = video[src[frame]] — float4 coalesced streaming copy.
__global__ __launch_bounds__(256) void gather_frames(
        const float4* __restrict__ video, const int* __restrict__ src,
        float4* __restrict__ out, int f4_per_frame) {
    int frame = blockIdx.y;
    int s = src[frame];                       // uniform per block
    size_t off = (size_t)blockIdx.x * blockDim.x + threadIdx.x;
    if (off < (size_t)f4_per_frame) {
        out[(size_t)frame * f4_per_frame + off] =
            video[(size_t)s * f4_per_frame + off];
    }
}

// Scalar fallback for F not divisible by 4 (not expected here).
__global__ __launch_bounds__(256) void gather_frames_scalar(
        const float* __restrict__ video, const int* __restrict__ src,
        float* __restrict__ out, int f_per_frame) {
    int frame = blockIdx.y;
    int s = src[frame];
    size_t off = (size_t)blockIdx.x * blockDim.x + threadIdx.x;
    if (off < (size_t)f_per_frame) {
        out[(size_t)frame * f_per_frame + off] =
            video[(size_t)s * f_per_frame + off];
    }
}

extern "C" void kernel_launch(void* const* d_in, const int* in_sizes, int n_in,
                              void* d_out, int out_size, void* d_ws, size_t ws_size,
                              hipStream_t stream) {
    const float* video = (const float*)d_in[0];
    const float* coin  = (const float*)d_in[1];
    const int*   nbr   = (const int*)d_in[2];
    float* out = (float*)d_out;

    int N = in_sizes[1];                 // 128 frames
    int F = in_sizes[0] / N;             // 3*512*512 = 786432 floats/frame
    int* src = (int*)d_ws;               // N ints of scratch

    resolve_src<<<1, N, 0, stream>>>(coin, nbr, src, N);

    if ((F & 3) == 0) {
        int f4 = F >> 2;                 // 196608 float4 per frame
        dim3 grid((unsigned)((f4 + 255) / 256), (unsigned)N);
        gather_frames<<<grid, 256, 0, stream>>>(
            (const float4*)video, src, (float4*)out, f4);
    } else {
        dim3 grid((unsigned)((F + 255) / 256), (unsigned)N);
        gather_frames_scalar<<<grid, 256, 0, stream>>>(video, src, out, F);
    }
}